// Round 1
// 2067.364 us; speedup vs baseline: 1.0286x; 1.0286x over previous
//
#include <hip/hip_runtime.h>
#include <math.h>

#define N_NODES 100000
#define N_EDGES 1600000
#define HID 128
#define VOCAB 1000
#define ROWSTR 1000   // floats per output row; also per-node scratch slot
#define NPAD 1024     // vocab padded to 64 MFMA 16-col tiles

// per-node scratch layout inside its own d_out row (floats 0..999):
//   [0..127]   h buffer A
//   [128..255] h buffer B
//   [256..767] CSR col storage: 512 ints/row, rows 0..3124 hold all 1.6M edges
//   [768] cnt (int)  [769] row_ptr (int)  [770] cursor (int)
//   [771] chunk sum  [772] chunk offset   (rows 0..97 only, for the scan)
#define OFF_H0   0
#define OFF_H1   128
#define OFF_COL  256
#define OFF_CNT  768
#define OFF_PTR  769
#define OFF_CUR  770
#define OFF_CSUM 771
#define OFF_COFF 772

#define TNB 8    // nodes per layer block
#define CHUNK 1024
#define NBLK  98  // ceil(100000/1024)

typedef __attribute__((ext_vector_type(8))) short bf16x8;  // 8 bf16 (4 VGPRs)
typedef __attribute__((ext_vector_type(4))) float f32x4;   // MFMA C/D frag

__device__ __forceinline__ int* meta(float* b, int i, int off) {
    return (int*)(b + (size_t)i * ROWSTR + off);
}
__device__ __forceinline__ int* colp(float* b, int pos) {
    return (int*)(b + (size_t)(pos >> 9) * ROWSTR + OFF_COL + (pos & 511));
}

// h0[i] = emb[x[i]]; cnt = 0
__global__ __launch_bounds__(HID) void k_embed(float* __restrict__ base,
                                               const int* __restrict__ x,
                                               const float* __restrict__ emb) {
    int i = blockIdx.x, j = threadIdx.x;
    base[(size_t)i * ROWSTR + OFF_H0 + j] = emb[x[i] * HID + j];
    if (j == 0) *meta(base, i, OFF_CNT) = 0;
}

// cnt[dst]++
__global__ __launch_bounds__(256) void k_hist(float* __restrict__ base,
                                              const int* __restrict__ dst) {
    int e = blockIdx.x * 256 + threadIdx.x;
    if (e < N_EDGES) atomicAdd(meta(base, dst[e], OFF_CNT), 1);
}

// chunkSum[b] = sum of cnt over chunk b
__global__ __launch_bounds__(256) void k_chunk_sums(float* __restrict__ base) {
    int b = blockIdx.x, t = threadIdx.x;
    int s = 0;
    #pragma unroll
    for (int u = 0; u < 4; ++u) {
        int i = b * CHUNK + t * 4 + u;
        if (i < N_NODES) s += *meta(base, i, OFF_CNT);
    }
    #pragma unroll
    for (int o = 32; o > 0; o >>= 1) s += __shfl_xor(s, o, 64);
    __shared__ int ws[4];
    int wave = t >> 6, lane = t & 63;
    if (lane == 0) ws[wave] = s;
    __syncthreads();
    if (t == 0) *meta(base, b, OFF_CSUM) = ws[0] + ws[1] + ws[2] + ws[3];
}

// serial exclusive scan of 98 chunk sums (tiny)
__global__ void k_scan_top(float* __restrict__ base) {
    if (threadIdx.x == 0) {
        int run = 0;
        for (int b = 0; b < NBLK; ++b) {
            int v = *meta(base, b, OFF_CSUM);
            *meta(base, b, OFF_COFF) = run;
            run += v;
        }
    }
}

// row_ptr / cursor = global exclusive prefix of cnt
__global__ __launch_bounds__(256) void k_scan_apply(float* __restrict__ base) {
    int b = blockIdx.x, t = threadIdx.x;
    int c[4];
    #pragma unroll
    for (int u = 0; u < 4; ++u) {
        int i = b * CHUNK + t * 4 + u;
        c[u] = (i < N_NODES) ? *meta(base, i, OFF_CNT) : 0;
    }
    int tsum = c[0] + c[1] + c[2] + c[3];
    __shared__ int sc[256];
    sc[t] = tsum;
    __syncthreads();
    for (int o = 1; o < 256; o <<= 1) {
        int v = (t >= o) ? sc[t - o] : 0;
        __syncthreads();
        sc[t] += v;
        __syncthreads();
    }
    int start = *meta(base, b, OFF_COFF) + (sc[t] - tsum);
    #pragma unroll
    for (int u = 0; u < 4; ++u) {
        int i = b * CHUNK + t * 4 + u;
        if (i < N_NODES) {
            *meta(base, i, OFF_PTR) = start;
            *meta(base, i, OFF_CUR) = start;
            start += c[u];
        }
    }
}

// col[cursor[dst]++] = src
__global__ __launch_bounds__(256) void k_build(float* __restrict__ base,
                                               const int* __restrict__ src,
                                               const int* __restrict__ dst) {
    int e = blockIdx.x * 256 + threadIdx.x;
    if (e >= N_EDGES) return;
    int pos = atomicAdd(meta(base, dst[e], OFF_CUR), 1);
    *colp(base, pos) = src[e];
}

// fused: mean-gather + h_out = relu(mean@Wl + bl + h_in@Wr)
__global__ __launch_bounds__(HID) void k_layer(float* __restrict__ base,
                                               const float* __restrict__ Wl,
                                               const float* __restrict__ bl,
                                               const float* __restrict__ Wr,
                                               int in_off, int out_off) {
    int j = threadIdx.x;
    int i0 = blockIdx.x * TNB;
    __shared__ __align__(16) float s_m[TNB][HID];
    __shared__ __align__(16) float s_h[TNB][HID];

    for (int r = 0; r < TNB; ++r) {
        int i = i0 + r;
        int beg = *meta(base, i, OFF_PTR);
        int c   = *meta(base, i, OFF_CNT);
        float a = 0.f;
        for (int e = beg; e < beg + c; ++e) {
            int s = *colp(base, e);
            a += base[(size_t)s * ROWSTR + in_off + j];
        }
        s_m[r][j] = a / fmaxf((float)c, 1.0f);
        s_h[r][j] = base[(size_t)i * ROWSTR + in_off + j];
    }
    __syncthreads();

    float acc[TNB];
    #pragma unroll
    for (int r = 0; r < TNB; ++r) acc[r] = 0.f;

    for (int k4 = 0; k4 < HID / 4; ++k4) {
        int k = 4 * k4;
        float wl0 = Wl[(k + 0) * HID + j];
        float wl1 = Wl[(k + 1) * HID + j];
        float wl2 = Wl[(k + 2) * HID + j];
        float wl3 = Wl[(k + 3) * HID + j];
        float wr0 = Wr[(k + 0) * HID + j];
        float wr1 = Wr[(k + 1) * HID + j];
        float wr2 = Wr[(k + 2) * HID + j];
        float wr3 = Wr[(k + 3) * HID + j];
        #pragma unroll
        for (int r = 0; r < TNB; ++r) {
            float4 mv = ((const float4*)s_m[r])[k4];
            float4 hv = ((const float4*)s_h[r])[k4];
            acc[r] += mv.x * wl0 + mv.y * wl1 + mv.z * wl2 + mv.w * wl3
                    + hv.x * wr0 + hv.y * wr1 + hv.z * wr2 + hv.w * wr3;
        }
    }

    float bb = bl[j];
    #pragma unroll
    for (int r = 0; r < TNB; ++r)
        base[(size_t)(i0 + r) * ROWSTR + out_off + j] = fmaxf(acc[r] + bb, 0.f);
}

// split Wlast [HID][VOCAB] fp32 -> transposed bf16 hi/lo [NPAD][HID] (pad cols zero)
__global__ __launch_bounds__(256) void k_wsplit(const float* __restrict__ Wlast,
                                                short* __restrict__ Wth,
                                                short* __restrict__ Wtl) {
    int idx = blockIdx.x * 256 + threadIdx.x;   // 0 .. NPAD*HID-1
    int k   = idx >> 10;                         // 0..127
    int col = idx & (NPAD - 1);                  // 0..1023
    float f = (col < VOCAB) ? Wlast[(size_t)k * VOCAB + col] : 0.f;
    unsigned b = __float_as_uint(f);
    short hi = (short)(b >> 16);                 // truncated bf16
    float fh = __uint_as_float(b & 0xFFFF0000u);
    short lo = (short)(__float_as_uint(f - fh) >> 16);
    Wth[(size_t)col * HID + k] = hi;
    Wtl[(size_t)col * HID + k] = lo;
}

// out[i] = softmax(h[i] @ Wlast + blast) via split-bf16 MFMA (3 products)
// block: 256 thr (4 waves), 16 nodes; wave w owns cols [w*256, w*256+256)
__global__ __launch_bounds__(256) void k_final_mfma(float* __restrict__ base,
                                                    const short* __restrict__ Wth,
                                                    const short* __restrict__ Wtl,
                                                    const float* __restrict__ blast,
                                                    int h_off) {
    const int t = threadIdx.x;
    const int lane = t & 63, w = t >> 6;
    const int i0 = blockIdx.x * 16;

    __shared__ __align__(16) short s_hi[16][HID + 8];
    __shared__ __align__(16) short s_lo[16][HID + 8];
    __shared__ float smax[4][16];
    __shared__ float ssum[4][16];

    // ---- load H tile [16][128], split to bf16 hi/lo in LDS (8 floats/thread)
    {
        int r = t >> 4, k0 = (t & 15) * 8;
        const float* hp = base + (size_t)(i0 + r) * ROWSTR + h_off + k0;
        float4 f0 = ((const float4*)hp)[0];
        float4 f1 = ((const float4*)hp)[1];
        float f[8] = {f0.x, f0.y, f0.z, f0.w, f1.x, f1.y, f1.z, f1.w};
        bf16x8 vh, vl;
        #pragma unroll
        for (int u = 0; u < 8; ++u) {
            unsigned b = __float_as_uint(f[u]);
            vh[u] = (short)(b >> 16);
            float fhv = __uint_as_float(b & 0xFFFF0000u);
            vl[u] = (short)(__float_as_uint(f[u] - fhv) >> 16);
        }
        *(bf16x8*)&s_hi[r][k0] = vh;
        *(bf16x8*)&s_lo[r][k0] = vl;
    }
    __syncthreads();

    // ---- A fragments: row = lane&15, k = (lane>>4)*8 + i, 4 K-steps of 32
    bf16x8 a_hi[4], a_lo[4];
    {
        int ar = lane & 15, ak = (lane >> 4) * 8;
        #pragma unroll
        for (int ks = 0; ks < 4; ++ks) {
            a_hi[ks] = *(const bf16x8*)&s_hi[ar][ks * 32 + ak];
            a_lo[ks] = *(const bf16x8*)&s_lo[ar][ks * 32 + ak];
        }
    }

    // ---- main MFMA loop: 16 N-tiles per wave, K=128, 3 split products
    f32x4 acc[16];
    #pragma unroll
    for (int tt = 0; tt < 16; ++tt) acc[tt] = (f32x4){0.f, 0.f, 0.f, 0.f};

    // B frag: col = lane&15 (of tile), k = (lane>>4)*8 + i; W stored [col][k]
    const int colbase = w * 256 + (lane & 15);
    const bf16x8* bh = (const bf16x8*)(Wth + (size_t)colbase * HID) + (lane >> 4);
    const bf16x8* bl = (const bf16x8*)(Wtl + (size_t)colbase * HID) + (lane >> 4);
    // tile stride: 16 cols * 128 shorts / 8 = 256 frags; kstep stride: 4 frags

    #pragma unroll
    for (int ks = 0; ks < 4; ++ks) {
        bf16x8 ah = a_hi[ks], al = a_lo[ks];
        #pragma unroll
        for (int tt = 0; tt < 16; ++tt) {
            bf16x8 wh = bh[tt * 256 + ks * 4];
            bf16x8 wl = bl[tt * 256 + ks * 4];
            acc[tt] = __builtin_amdgcn_mfma_f32_16x16x32_bf16(ah, wh, acc[tt], 0, 0, 0);
            acc[tt] = __builtin_amdgcn_mfma_f32_16x16x32_bf16(al, wh, acc[tt], 0, 0, 0);
            acc[tt] = __builtin_amdgcn_mfma_f32_16x16x32_bf16(ah, wl, acc[tt], 0, 0, 0);
        }
    }

    // ---- bias (per column; all 4 C rows share the lane's column)
    #pragma unroll
    for (int tt = 0; tt < 16; ++tt) {
        int col = w * 256 + tt * 16 + (lane & 15);
        float bb = (col < VOCAB) ? blast[col] : 0.f;
        acc[tt][0] += bb; acc[tt][1] += bb; acc[tt][2] += bb; acc[tt][3] += bb;
    }

    // ---- softmax. C layout: col = lane&15, row = (lane>>4)*4 + r
    float pm[4];
    #pragma unroll
    for (int r = 0; r < 4; ++r) pm[r] = -INFINITY;
    #pragma unroll
    for (int tt = 0; tt < 16; ++tt) {
        int col = w * 256 + tt * 16 + (lane & 15);
        if (col < VOCAB) {
            #pragma unroll
            for (int r = 0; r < 4; ++r) pm[r] = fmaxf(pm[r], acc[tt][r]);
        }
    }
    #pragma unroll
    for (int s = 1; s < 16; s <<= 1)
        #pragma unroll
        for (int r = 0; r < 4; ++r)
            pm[r] = fmaxf(pm[r], __shfl_xor(pm[r], s, 64));
    if ((lane & 15) == 0) {
        #pragma unroll
        for (int r = 0; r < 4; ++r) smax[w][(lane >> 4) * 4 + r] = pm[r];
    }
    __syncthreads();
    float M[4];
    #pragma unroll
    for (int r = 0; r < 4; ++r) {
        int row = (lane >> 4) * 4 + r;
        M[r] = fmaxf(fmaxf(smax[0][row], smax[1][row]),
                     fmaxf(smax[2][row], smax[3][row]));
    }

    float ps[4] = {0.f, 0.f, 0.f, 0.f};
    #pragma unroll
    for (int tt = 0; tt < 16; ++tt) {
        int col = w * 256 + tt * 16 + (lane & 15);
        bool valid = (col < VOCAB);
        #pragma unroll
        for (int r = 0; r < 4; ++r) {
            float e = valid ? __expf(acc[tt][r] - M[r]) : 0.f;
            acc[tt][r] = e;
            ps[r] += e;
        }
    }
    #pragma unroll
    for (int s = 1; s < 16; s <<= 1)
        #pragma unroll
        for (int r = 0; r < 4; ++r)
            ps[r] += __shfl_xor(ps[r], s, 64);
    if ((lane & 15) == 0) {
        #pragma unroll
        for (int r = 0; r < 4; ++r) ssum[w][(lane >> 4) * 4 + r] = ps[r];
    }
    __syncthreads();
    float inv[4];
    #pragma unroll
    for (int r = 0; r < 4; ++r) {
        int row = (lane >> 4) * 4 + r;
        float S = (ssum[0][row] + ssum[1][row]) + (ssum[2][row] + ssum[3][row]);
        inv[r] = 1.0f / S;
    }

    // ---- store (masked pad cols), overwrites the full output rows
    #pragma unroll
    for (int tt = 0; tt < 16; ++tt) {
        int col = w * 256 + tt * 16 + (lane & 15);
        if (col < VOCAB) {
            #pragma unroll
            for (int r = 0; r < 4; ++r) {
                int row = (lane >> 4) * 4 + r;
                base[(size_t)(i0 + row) * ROWSTR + col] = acc[tt][r] * inv[r];
            }
        }
    }
}

extern "C" void kernel_launch(void* const* d_in, const int* in_sizes, int n_in,
                              void* d_out, int out_size, void* d_ws, size_t ws_size,
                              hipStream_t stream) {
    (void)in_sizes; (void)n_in; (void)out_size; (void)ws_size;
    const int*   x     = (const int*)d_in[0];
    const int*   ei    = (const int*)d_in[1];
    const float* emb   = (const float*)d_in[2];
    const float* Wl    = (const float*)d_in[3];
    const float* bl    = (const float*)d_in[4];
    const float* Wr    = (const float*)d_in[5];
    const float* Wlast = (const float*)d_in[6];
    const float* blast = (const float*)d_in[7];
    float* base = (float*)d_out;
    const int* src = ei;
    const int* dst = ei + N_EDGES;

    short* Wth = (short*)d_ws;                       // [NPAD][HID] bf16 hi
    short* Wtl = Wth + (size_t)NPAD * HID;           // [NPAD][HID] bf16 lo

    const int EG = (N_EDGES + 255) / 256;

    k_wsplit<<<dim3(NPAD * HID / 256), dim3(256), 0, stream>>>(Wlast, Wth, Wtl);
    k_embed<<<dim3(N_NODES), dim3(HID), 0, stream>>>(base, x, emb);
    k_hist<<<dim3(EG), dim3(256), 0, stream>>>(base, dst);
    k_chunk_sums<<<dim3(NBLK), dim3(256), 0, stream>>>(base);
    k_scan_top<<<dim3(1), dim3(64), 0, stream>>>(base);
    k_scan_apply<<<dim3(NBLK), dim3(256), 0, stream>>>(base);
    k_build<<<dim3(EG), dim3(256), 0, stream>>>(base, src, dst);

    int in_off = OFF_H0, out_off = OFF_H1;
    for (int l = 0; l < 3; ++l) {
        k_layer<<<dim3(N_NODES / TNB), dim3(HID), 0, stream>>>(
            base, Wl + (size_t)l * HID * HID, bl + (size_t)l * HID,
            Wr + (size_t)l * HID * HID, in_off, out_off);
        int tmp = in_off; in_off = out_off; out_off = tmp;
    }
    // after 3 layers h lives at in_off (== OFF_H1)
    k_final_mfma<<<dim3(N_NODES / 16), dim3(256), 0, stream>>>(
        base, Wth, Wtl, blast, in_off);
}

// Round 2
// 1868.459 us; speedup vs baseline: 1.1381x; 1.1065x over previous
//
#include <hip/hip_runtime.h>
#include <math.h>

#define N_NODES 100000
#define N_EDGES 1600000
#define HID 128
#define VOCAB 1000
#define ROWSTR 1000   // floats per output row; also per-node scratch slot
#define NPAD 1024     // vocab padded to 64 MFMA 16-col tiles

// per-node scratch layout inside its own d_out row (floats 0..999):
//   [0..127]   h buffer A
//   [128..255] h buffer B
//   [256..767] CSR col storage: 512 ints/row, rows 0..3124 hold all 1.6M edges
//   [768] cnt (int)  [769] row_ptr (int)  [770] cursor (int)
//   [771] chunk sum  [772] chunk offset   (rows 0..97 only, for the scan)
#define OFF_H0   0
#define OFF_H1   128
#define OFF_COL  256
#define OFF_CNT  768
#define OFF_PTR  769
#define OFF_CUR  770
#define OFF_CSUM 771
#define OFF_COFF 772

#define TNB 8    // nodes per layer block
#define CHUNK 1024
#define NBLK  98  // ceil(100000/1024)

typedef __attribute__((ext_vector_type(8))) short bf16x8;  // 8 bf16 (4 VGPRs)
typedef __attribute__((ext_vector_type(4))) float f32x4;   // MFMA C/D frag

__device__ __forceinline__ int* meta(float* b, int i, int off) {
    return (int*)(b + (size_t)i * ROWSTR + off);
}
__device__ __forceinline__ int* colp(float* b, int pos) {
    return (int*)(b + (size_t)(pos >> 9) * ROWSTR + OFF_COL + (pos & 511));
}

// async global->LDS, 16 bytes per lane (linear LDS dest = base + lane*16)
__device__ __forceinline__ void gload16(const void* g, void* l) {
    __builtin_amdgcn_global_load_lds(
        (const __attribute__((address_space(1))) unsigned int*)g,
        (__attribute__((address_space(3))) unsigned int*)l, 16, 0, 0);
}

// h0[i] = emb[x[i]]; cnt = 0
__global__ __launch_bounds__(HID) void k_embed(float* __restrict__ base,
                                               const int* __restrict__ x,
                                               const float* __restrict__ emb) {
    int i = blockIdx.x, j = threadIdx.x;
    base[(size_t)i * ROWSTR + OFF_H0 + j] = emb[x[i] * HID + j];
    if (j == 0) *meta(base, i, OFF_CNT) = 0;
}

// cnt[dst]++
__global__ __launch_bounds__(256) void k_hist(float* __restrict__ base,
                                              const int* __restrict__ dst) {
    int e = blockIdx.x * 256 + threadIdx.x;
    if (e < N_EDGES) atomicAdd(meta(base, dst[e], OFF_CNT), 1);
}

// chunkSum[b] = sum of cnt over chunk b
__global__ __launch_bounds__(256) void k_chunk_sums(float* __restrict__ base) {
    int b = blockIdx.x, t = threadIdx.x;
    int s = 0;
    #pragma unroll
    for (int u = 0; u < 4; ++u) {
        int i = b * CHUNK + t * 4 + u;
        if (i < N_NODES) s += *meta(base, i, OFF_CNT);
    }
    #pragma unroll
    for (int o = 32; o > 0; o >>= 1) s += __shfl_xor(s, o, 64);
    __shared__ int ws[4];
    int wave = t >> 6, lane = t & 63;
    if (lane == 0) ws[wave] = s;
    __syncthreads();
    if (t == 0) *meta(base, b, OFF_CSUM) = ws[0] + ws[1] + ws[2] + ws[3];
}

// serial exclusive scan of 98 chunk sums (tiny)
__global__ void k_scan_top(float* __restrict__ base) {
    if (threadIdx.x == 0) {
        int run = 0;
        for (int b = 0; b < NBLK; ++b) {
            int v = *meta(base, b, OFF_CSUM);
            *meta(base, b, OFF_COFF) = run;
            run += v;
        }
    }
}

// row_ptr / cursor = global exclusive prefix of cnt
__global__ __launch_bounds__(256) void k_scan_apply(float* __restrict__ base) {
    int b = blockIdx.x, t = threadIdx.x;
    int c[4];
    #pragma unroll
    for (int u = 0; u < 4; ++u) {
        int i = b * CHUNK + t * 4 + u;
        c[u] = (i < N_NODES) ? *meta(base, i, OFF_CNT) : 0;
    }
    int tsum = c[0] + c[1] + c[2] + c[3];
    __shared__ int sc[256];
    sc[t] = tsum;
    __syncthreads();
    for (int o = 1; o < 256; o <<= 1) {
        int v = (t >= o) ? sc[t - o] : 0;
        __syncthreads();
        sc[t] += v;
        __syncthreads();
    }
    int start = *meta(base, b, OFF_COFF) + (sc[t] - tsum);
    #pragma unroll
    for (int u = 0; u < 4; ++u) {
        int i = b * CHUNK + t * 4 + u;
        if (i < N_NODES) {
            *meta(base, i, OFF_PTR) = start;
            *meta(base, i, OFF_CUR) = start;
            start += c[u];
        }
    }
}

// col[cursor[dst]++] = src
__global__ __launch_bounds__(256) void k_build(float* __restrict__ base,
                                               const int* __restrict__ src,
                                               const int* __restrict__ dst) {
    int e = blockIdx.x * 256 + threadIdx.x;
    if (e >= N_EDGES) return;
    int pos = atomicAdd(meta(base, dst[e], OFF_CUR), 1);
    *colp(base, pos) = src[e];
}

// fused: mean-gather + h_out = relu(mean@Wl + bl + h_in@Wr)
__global__ __launch_bounds__(HID) void k_layer(float* __restrict__ base,
                                               const float* __restrict__ Wl,
                                               const float* __restrict__ bl,
                                               const float* __restrict__ Wr,
                                               int in_off, int out_off) {
    int j = threadIdx.x;
    int i0 = blockIdx.x * TNB;
    __shared__ __align__(16) float s_m[TNB][HID];
    __shared__ __align__(16) float s_h[TNB][HID];

    for (int r = 0; r < TNB; ++r) {
        int i = i0 + r;
        int beg = *meta(base, i, OFF_PTR);
        int c   = *meta(base, i, OFF_CNT);
        int e = beg, end = beg + c;
        // 4-way unrolled gather: 4 independent loads in flight (L3-latency bound)
        float a0 = 0.f, a1 = 0.f, a2 = 0.f, a3 = 0.f;
        for (; e + 4 <= end; e += 4) {
            int s0 = *colp(base, e + 0);
            int s1 = *colp(base, e + 1);
            int s2 = *colp(base, e + 2);
            int s3 = *colp(base, e + 3);
            a0 += base[(size_t)s0 * ROWSTR + in_off + j];
            a1 += base[(size_t)s1 * ROWSTR + in_off + j];
            a2 += base[(size_t)s2 * ROWSTR + in_off + j];
            a3 += base[(size_t)s3 * ROWSTR + in_off + j];
        }
        for (; e < end; ++e)
            a0 += base[(size_t)(*colp(base, e)) * ROWSTR + in_off + j];
        float a = (a0 + a1) + (a2 + a3);
        s_m[r][j] = a / fmaxf((float)c, 1.0f);
        s_h[r][j] = base[(size_t)i * ROWSTR + in_off + j];
    }
    __syncthreads();

    float acc[TNB];
    #pragma unroll
    for (int r = 0; r < TNB; ++r) acc[r] = 0.f;

    for (int k4 = 0; k4 < HID / 4; ++k4) {
        int k = 4 * k4;
        float wl0 = Wl[(k + 0) * HID + j];
        float wl1 = Wl[(k + 1) * HID + j];
        float wl2 = Wl[(k + 2) * HID + j];
        float wl3 = Wl[(k + 3) * HID + j];
        float wr0 = Wr[(k + 0) * HID + j];
        float wr1 = Wr[(k + 1) * HID + j];
        float wr2 = Wr[(k + 2) * HID + j];
        float wr3 = Wr[(k + 3) * HID + j];
        #pragma unroll
        for (int r = 0; r < TNB; ++r) {
            float4 mv = ((const float4*)s_m[r])[k4];
            float4 hv = ((const float4*)s_h[r])[k4];
            acc[r] += mv.x * wl0 + mv.y * wl1 + mv.z * wl2 + mv.w * wl3
                    + hv.x * wr0 + hv.y * wr1 + hv.z * wr2 + hv.w * wr3;
        }
    }

    float bb = bl[j];
    #pragma unroll
    for (int r = 0; r < TNB; ++r)
        base[(size_t)(i0 + r) * ROWSTR + out_off + j] = fmaxf(acc[r] + bb, 0.f);
}

// split Wlast [HID][VOCAB] fp32 -> transposed bf16 hi/lo [NPAD][HID] (pad cols zero)
__global__ __launch_bounds__(256) void k_wsplit(const float* __restrict__ Wlast,
                                                short* __restrict__ Wth,
                                                short* __restrict__ Wtl) {
    int idx = blockIdx.x * 256 + threadIdx.x;   // 0 .. NPAD*HID-1
    int k   = idx >> 10;                         // 0..127
    int col = idx & (NPAD - 1);                  // 0..1023
    float f = (col < VOCAB) ? Wlast[(size_t)k * VOCAB + col] : 0.f;
    unsigned b = __float_as_uint(f);
    short hi = (short)(b >> 16);                 // truncated bf16
    float fh = __uint_as_float(b & 0xFFFF0000u);
    short lo = (short)(__float_as_uint(f - fh) >> 16);
    Wth[(size_t)col * HID + k] = hi;
    Wtl[(size_t)col * HID + k] = lo;
}

// out[i] = softmax(h[i] @ Wlast + blast) via split-bf16 MFMA (3 products)
// block: 512 thr (8 waves = 4 col-groups x 2 row-groups), 32 nodes.
// W streamed global->LDS in 4 K-chunks of 32 (hi+lo = 128 KB), layout
// [k-quad][col] so B-frag ds_read_b128 is contiguous per 16 lanes.
__global__ __launch_bounds__(512) void k_final_mfma(float* __restrict__ base,
                                                    const short* __restrict__ Wth,
                                                    const short* __restrict__ Wtl,
                                                    const float* __restrict__ blast,
                                                    int h_off) {
    const int t = threadIdx.x;
    const int lane = t & 63, w = t >> 6;
    const int cg = w & 3;        // col group: cols [cg*256, cg*256+256)
    const int rg = w >> 2;       // row group: rows [rg*16, rg*16+16)
    const int q = lane >> 4;     // k-quad within a 32-K step
    const int i0 = blockIdx.x * 32;

    // [hi/lo][quad q][col] 16B units: (q*1024+col)*8 shorts
    __shared__ short sW[2][4096 * 8];           // 128 KB
    __shared__ float smax[4][32];
    __shared__ float ssum[4][32];

    // ---- issue stage of K-chunk 0 (each thread: 8 hi + 8 lo units of 16B)
    #pragma unroll
    for (int jj = 0; jj < 8; ++jj) {
        int u = t + jj * 512;                    // unit 0..4095
        int col = u & 1023, uq = u >> 10;
        size_t goff = (size_t)col * HID + 0 * 32 + uq * 8;   // shorts
        gload16(Wth + goff, &sW[0][(size_t)u * 8]);
        gload16(Wtl + goff, &sW[1][(size_t)u * 8]);
    }

    // ---- A fragments straight from global, split to bf16 hi/lo in regs.
    // A layout: row = lane&15 (+rg*16), k = kc*32 + q*8 + i
    bf16x8 ah[4], al[4];
    {
        const int arow = i0 + rg * 16 + (lane & 15);
        const float* hrow = base + (size_t)arow * ROWSTR + h_off + q * 8;
        #pragma unroll
        for (int kc = 0; kc < 4; ++kc) {
            float4 f0 = ((const float4*)(hrow + kc * 32))[0];
            float4 f1 = ((const float4*)(hrow + kc * 32))[1];
            float f[8] = {f0.x, f0.y, f0.z, f0.w, f1.x, f1.y, f1.z, f1.w};
            #pragma unroll
            for (int u2 = 0; u2 < 8; ++u2) {
                unsigned b = __float_as_uint(f[u2]);
                ah[kc][u2] = (short)(b >> 16);
                float fhv = __uint_as_float(b & 0xFFFF0000u);
                al[kc][u2] = (short)(__float_as_uint(f[u2] - fhv) >> 16);
            }
        }
    }

    f32x4 acc[16];
    #pragma unroll
    for (int tt = 0; tt < 16; ++tt) acc[tt] = (f32x4){0.f, 0.f, 0.f, 0.f};

    // ---- K-chunk loop: wait chunk, 48 MFMA, stage next
    #pragma unroll
    for (int kc = 0; kc < 4; ++kc) {
        asm volatile("s_waitcnt vmcnt(0)" ::: "memory");
        __syncthreads();                         // chunk kc staged for all
        #pragma unroll
        for (int tt = 0; tt < 16; ++tt) {
            int col = cg * 256 + tt * 16 + (lane & 15);
            bf16x8 wh = *(const bf16x8*)&sW[0][((size_t)q * 1024 + col) * 8];
            bf16x8 wl = *(const bf16x8*)&sW[1][((size_t)q * 1024 + col) * 8];
            acc[tt] = __builtin_amdgcn_mfma_f32_16x16x32_bf16(ah[kc], wh, acc[tt], 0, 0, 0);
            acc[tt] = __builtin_amdgcn_mfma_f32_16x16x32_bf16(al[kc], wh, acc[tt], 0, 0, 0);
            acc[tt] = __builtin_amdgcn_mfma_f32_16x16x32_bf16(ah[kc], wl, acc[tt], 0, 0, 0);
        }
        if (kc < 3) {
            __syncthreads();                     // all waves done reading kc
            #pragma unroll
            for (int jj = 0; jj < 8; ++jj) {
                int u = t + jj * 512;
                int col = u & 1023, uq = u >> 10;
                size_t goff = (size_t)col * HID + (kc + 1) * 32 + uq * 8;
                gload16(Wth + goff, &sW[0][(size_t)u * 8]);
                gload16(Wtl + goff, &sW[1][(size_t)u * 8]);
            }
        }
    }

    // ---- bias (per column; all 4 C rows share the lane's column)
    #pragma unroll
    for (int tt = 0; tt < 16; ++tt) {
        int col = cg * 256 + tt * 16 + (lane & 15);
        float bb = (col < VOCAB) ? blast[col] : 0.f;
        acc[tt][0] += bb; acc[tt][1] += bb; acc[tt][2] += bb; acc[tt][3] += bb;
    }

    // ---- softmax. C layout: col = lane&15, row-in-tile = q*4 + r
    float pm[4];
    #pragma unroll
    for (int r = 0; r < 4; ++r) pm[r] = -INFINITY;
    #pragma unroll
    for (int tt = 0; tt < 16; ++tt) {
        int col = cg * 256 + tt * 16 + (lane & 15);
        if (col < VOCAB) {
            #pragma unroll
            for (int r = 0; r < 4; ++r) pm[r] = fmaxf(pm[r], acc[tt][r]);
        }
    }
    #pragma unroll
    for (int s = 1; s < 16; s <<= 1)
        #pragma unroll
        for (int r = 0; r < 4; ++r)
            pm[r] = fmaxf(pm[r], __shfl_xor(pm[r], s, 64));
    if ((lane & 15) == 0) {
        #pragma unroll
        for (int r = 0; r < 4; ++r) smax[cg][rg * 16 + q * 4 + r] = pm[r];
    }
    __syncthreads();
    float M[4];
    #pragma unroll
    for (int r = 0; r < 4; ++r) {
        int row = rg * 16 + q * 4 + r;
        M[r] = fmaxf(fmaxf(smax[0][row], smax[1][row]),
                     fmaxf(smax[2][row], smax[3][row]));
    }

    float ps[4] = {0.f, 0.f, 0.f, 0.f};
    #pragma unroll
    for (int tt = 0; tt < 16; ++tt) {
        int col = cg * 256 + tt * 16 + (lane & 15);
        bool valid = (col < VOCAB);
        #pragma unroll
        for (int r = 0; r < 4; ++r) {
            float e = valid ? __expf(acc[tt][r] - M[r]) : 0.f;
            acc[tt][r] = e;
            ps[r] += e;
        }
    }
    #pragma unroll
    for (int s = 1; s < 16; s <<= 1)
        #pragma unroll
        for (int r = 0; r < 4; ++r)
            ps[r] += __shfl_xor(ps[r], s, 64);
    if ((lane & 15) == 0) {
        #pragma unroll
        for (int r = 0; r < 4; ++r) ssum[cg][rg * 16 + q * 4 + r] = ps[r];
    }
    __syncthreads();
    float inv[4];
    #pragma unroll
    for (int r = 0; r < 4; ++r) {
        int row = rg * 16 + q * 4 + r;
        float S = (ssum[0][row] + ssum[1][row]) + (ssum[2][row] + ssum[3][row]);
        inv[r] = 1.0f / S;
    }

    // ---- store (masked pad cols), overwrites the full output rows
    #pragma unroll
    for (int tt = 0; tt < 16; ++tt) {
        int col = cg * 256 + tt * 16 + (lane & 15);
        if (col < VOCAB) {
            #pragma unroll
            for (int r = 0; r < 4; ++r) {
                int row = i0 + rg * 16 + q * 4 + r;
                base[(size_t)row * ROWSTR + col] = acc[tt][r] * inv[r];
            }
        }
    }
}

extern "C" void kernel_launch(void* const* d_in, const int* in_sizes, int n_in,
                              void* d_out, int out_size, void* d_ws, size_t ws_size,
                              hipStream_t stream) {
    (void)in_sizes; (void)n_in; (void)out_size; (void)ws_size;
    const int*   x     = (const int*)d_in[0];
    const int*   ei    = (const int*)d_in[1];
    const float* emb   = (const float*)d_in[2];
    const float* Wl    = (const float*)d_in[3];
    const float* bl    = (const float*)d_in[4];
    const float* Wr    = (const float*)d_in[5];
    const float* Wlast = (const float*)d_in[6];
    const float* blast = (const float*)d_in[7];
    float* base = (float*)d_out;
    const int* src = ei;
    const int* dst = ei + N_EDGES;

    short* Wth = (short*)d_ws;                       // [NPAD][HID] bf16 hi
    short* Wtl = Wth + (size_t)NPAD * HID;           // [NPAD][HID] bf16 lo

    const int EG = (N_EDGES + 255) / 256;

    k_wsplit<<<dim3(NPAD * HID / 256), dim3(256), 0, stream>>>(Wlast, Wth, Wtl);
    k_embed<<<dim3(N_NODES), dim3(HID), 0, stream>>>(base, x, emb);
    k_hist<<<dim3(EG), dim3(256), 0, stream>>>(base, dst);
    k_chunk_sums<<<dim3(NBLK), dim3(256), 0, stream>>>(base);
    k_scan_top<<<dim3(1), dim3(64), 0, stream>>>(base);
    k_scan_apply<<<dim3(NBLK), dim3(256), 0, stream>>>(base);
    k_build<<<dim3(EG), dim3(256), 0, stream>>>(base, src, dst);

    int in_off = OFF_H0, out_off = OFF_H1;
    for (int l = 0; l < 3; ++l) {
        k_layer<<<dim3(N_NODES / TNB), dim3(HID), 0, stream>>>(
            base, Wl + (size_t)l * HID * HID, bl + (size_t)l * HID,
            Wr + (size_t)l * HID * HID, in_off, out_off);
        int tmp = in_off; in_off = out_off; out_off = tmp;
    }
    // after 3 layers h lives at in_off (== OFF_H1)
    k_final_mfma<<<dim3(N_NODES / 32), dim3(512), 0, stream>>>(
        base, Wth, Wtl, blast, in_off);
}

// Round 3
// 1542.432 us; speedup vs baseline: 1.3787x; 1.2114x over previous
//
#include <hip/hip_runtime.h>
#include <math.h>

#define N_NODES 100000
#define N_EDGES 1600000
#define HID 128
#define VOCAB 1000
#define ROWSTR 1000   // floats per output row; also per-node scratch slot
#define NPAD 1024     // vocab padded to 64 MFMA 16-col tiles

// per-node scratch layout inside its own d_out row (floats 0..999):
//   [0..127]   h buffer A
//   [128..255] h buffer B
//   [256..767] CSR col storage: 512 ints/row, rows 0..3124 hold all 1.6M edges
//   [768] cnt (int)  [769] row_ptr (int)  [770] cursor (int)
//   [771] chunk sum  [772] chunk offset   (rows 0..97 only, for the scan)
#define OFF_H0   0
#define OFF_H1   128
#define OFF_COL  256
#define OFF_CNT  768
#define OFF_PTR  769
#define OFF_CUR  770
#define OFF_CSUM 771
#define OFF_COFF 772

#define TNB 8    // nodes per layer block
#define CHUNK 1024
#define NBLK  98  // ceil(100000/1024)

typedef __attribute__((ext_vector_type(8))) short bf16x8;  // 8 bf16 (4 VGPRs)
typedef __attribute__((ext_vector_type(4))) float f32x4;   // MFMA C/D frag

__device__ __forceinline__ int* meta(float* b, int i, int off) {
    return (int*)(b + (size_t)i * ROWSTR + off);
}
__device__ __forceinline__ int* colp(float* b, int pos) {
    return (int*)(b + (size_t)(pos >> 9) * ROWSTR + OFF_COL + (pos & 511));
}

// async global->LDS, 16 bytes per lane (linear LDS dest = base + lane*16)
__device__ __forceinline__ void gload16(const void* g, void* l) {
    __builtin_amdgcn_global_load_lds(
        (const __attribute__((address_space(1))) unsigned int*)g,
        (__attribute__((address_space(3))) unsigned int*)l, 16, 0, 0);
}

// h0[i] = emb[x[i]]; cnt = 0
__global__ __launch_bounds__(HID) void k_embed(float* __restrict__ base,
                                               const int* __restrict__ x,
                                               const float* __restrict__ emb) {
    int i = blockIdx.x, j = threadIdx.x;
    base[(size_t)i * ROWSTR + OFF_H0 + j] = emb[x[i] * HID + j];
    if (j == 0) *meta(base, i, OFF_CNT) = 0;
}

// cnt[dst]++
__global__ __launch_bounds__(256) void k_hist(float* __restrict__ base,
                                              const int* __restrict__ dst) {
    int e = blockIdx.x * 256 + threadIdx.x;
    if (e < N_EDGES) atomicAdd(meta(base, dst[e], OFF_CNT), 1);
}

// chunkSum[b] = sum of cnt over chunk b
__global__ __launch_bounds__(256) void k_chunk_sums(float* __restrict__ base) {
    int b = blockIdx.x, t = threadIdx.x;
    int s = 0;
    #pragma unroll
    for (int u = 0; u < 4; ++u) {
        int i = b * CHUNK + t * 4 + u;
        if (i < N_NODES) s += *meta(base, i, OFF_CNT);
    }
    #pragma unroll
    for (int o = 32; o > 0; o >>= 1) s += __shfl_xor(s, o, 64);
    __shared__ int ws[4];
    int wave = t >> 6, lane = t & 63;
    if (lane == 0) ws[wave] = s;
    __syncthreads();
    if (t == 0) *meta(base, b, OFF_CSUM) = ws[0] + ws[1] + ws[2] + ws[3];
}

// serial exclusive scan of 98 chunk sums (tiny)
__global__ void k_scan_top(float* __restrict__ base) {
    if (threadIdx.x == 0) {
        int run = 0;
        for (int b = 0; b < NBLK; ++b) {
            int v = *meta(base, b, OFF_CSUM);
            *meta(base, b, OFF_COFF) = run;
            run += v;
        }
    }
}

// row_ptr / cursor = global exclusive prefix of cnt
__global__ __launch_bounds__(256) void k_scan_apply(float* __restrict__ base) {
    int b = blockIdx.x, t = threadIdx.x;
    int c[4];
    #pragma unroll
    for (int u = 0; u < 4; ++u) {
        int i = b * CHUNK + t * 4 + u;
        c[u] = (i < N_NODES) ? *meta(base, i, OFF_CNT) : 0;
    }
    int tsum = c[0] + c[1] + c[2] + c[3];
    __shared__ int sc[256];
    sc[t] = tsum;
    __syncthreads();
    for (int o = 1; o < 256; o <<= 1) {
        int v = (t >= o) ? sc[t - o] : 0;
        __syncthreads();
        sc[t] += v;
        __syncthreads();
    }
    int start = *meta(base, b, OFF_COFF) + (sc[t] - tsum);
    #pragma unroll
    for (int u = 0; u < 4; ++u) {
        int i = b * CHUNK + t * 4 + u;
        if (i < N_NODES) {
            *meta(base, i, OFF_PTR) = start;
            *meta(base, i, OFF_CUR) = start;
            start += c[u];
        }
    }
}

// col[cursor[dst]++] = src
__global__ __launch_bounds__(256) void k_build(float* __restrict__ base,
                                               const int* __restrict__ src,
                                               const int* __restrict__ dst) {
    int e = blockIdx.x * 256 + threadIdx.x;
    if (e >= N_EDGES) return;
    int pos = atomicAdd(meta(base, dst[e], OFF_CUR), 1);
    *colp(base, pos) = src[e];
}

// fused: mean-gather + h_out = relu(mean@Wl + bl + h_in@Wr)
// 256 threads = 4 waves; gather phase: one WAVE per node (float2 per lane),
// with software-pipelined column-index prefetch (breaks idx->gather chain).
__global__ __launch_bounds__(256) void k_layer(float* __restrict__ base,
                                               const float* __restrict__ Wl,
                                               const float* __restrict__ bl,
                                               const float* __restrict__ Wr,
                                               int in_off, int out_off) {
    const int t = threadIdx.x;
    const int wv = t >> 6, lane = t & 63;
    const int i0 = blockIdx.x * TNB;
    __shared__ __align__(16) float s_m[TNB][HID];
    __shared__ __align__(16) float s_h[TNB][HID];

    #pragma unroll
    for (int rr = 0; rr < TNB / 4; ++rr) {
        const int r = rr * 4 + wv;
        const int i = i0 + r;
        int beg = *meta(base, i, OFF_PTR);
        int c   = *meta(base, i, OFF_CNT);
        int e = beg, end = beg + c;
        float ax0=0.f, ay0=0.f, ax1=0.f, ay1=0.f;
        float ax2=0.f, ay2=0.f, ax3=0.f, ay3=0.f;
        int sA0=0, sA1=0, sA2=0, sA3=0;
        bool have = (e + 4 <= end);
        if (have) {
            sA0 = *colp(base, e + 0); sA1 = *colp(base, e + 1);
            sA2 = *colp(base, e + 2); sA3 = *colp(base, e + 3);
        }
        while (have) {
            bool haveN = (e + 8 <= end);
            int n0=0, n1=0, n2=0, n3=0;
            if (haveN) {
                n0 = *colp(base, e + 4); n1 = *colp(base, e + 5);
                n2 = *colp(base, e + 6); n3 = *colp(base, e + 7);
            }
            float2 v0 = *(const float2*)&base[(size_t)sA0 * ROWSTR + in_off + 2 * lane];
            float2 v1 = *(const float2*)&base[(size_t)sA1 * ROWSTR + in_off + 2 * lane];
            float2 v2 = *(const float2*)&base[(size_t)sA2 * ROWSTR + in_off + 2 * lane];
            float2 v3 = *(const float2*)&base[(size_t)sA3 * ROWSTR + in_off + 2 * lane];
            ax0 += v0.x; ay0 += v0.y; ax1 += v1.x; ay1 += v1.y;
            ax2 += v2.x; ay2 += v2.y; ax3 += v3.x; ay3 += v3.y;
            e += 4;
            sA0 = n0; sA1 = n1; sA2 = n2; sA3 = n3;
            have = haveN;
        }
        for (; e < end; ++e) {
            int s = *colp(base, e);
            float2 v = *(const float2*)&base[(size_t)s * ROWSTR + in_off + 2 * lane];
            ax0 += v.x; ay0 += v.y;
        }
        float invc = 1.0f / fmaxf((float)c, 1.0f);
        s_m[r][2 * lane + 0] = (ax0 + ax1 + ax2 + ax3) * invc;
        s_m[r][2 * lane + 1] = (ay0 + ay1 + ay2 + ay3) * invc;
        float2 hv = *(const float2*)&base[(size_t)i * ROWSTR + in_off + 2 * lane];
        s_h[r][2 * lane + 0] = hv.x;
        s_h[r][2 * lane + 1] = hv.y;
    }
    __syncthreads();

    // matmul: col j = t&127, thread-half owns 4 rows
    const int j = t & 127;
    const int r0 = (t >> 7) * 4;
    float acc[4] = {0.f, 0.f, 0.f, 0.f};
    for (int k4 = 0; k4 < HID / 4; ++k4) {
        int k = 4 * k4;
        float wl0 = Wl[(k + 0) * HID + j];
        float wl1 = Wl[(k + 1) * HID + j];
        float wl2 = Wl[(k + 2) * HID + j];
        float wl3 = Wl[(k + 3) * HID + j];
        float wr0 = Wr[(k + 0) * HID + j];
        float wr1 = Wr[(k + 1) * HID + j];
        float wr2 = Wr[(k + 2) * HID + j];
        float wr3 = Wr[(k + 3) * HID + j];
        #pragma unroll
        for (int r = 0; r < 4; ++r) {
            float4 mv = ((const float4*)s_m[r0 + r])[k4];
            float4 hv = ((const float4*)s_h[r0 + r])[k4];
            acc[r] += mv.x * wl0 + mv.y * wl1 + mv.z * wl2 + mv.w * wl3
                    + hv.x * wr0 + hv.y * wr1 + hv.z * wr2 + hv.w * wr3;
        }
    }
    float bb = bl[j];
    #pragma unroll
    for (int r = 0; r < 4; ++r)
        base[(size_t)(i0 + r0 + r) * ROWSTR + out_off + j] = fmaxf(acc[r] + bb, 0.f);
}

// split Wlast [HID][VOCAB] fp32 -> pre-swizzled bf16 units in ws.
// Wsw layout: unit index u = ((kc*2+half)*4096 + q*1024 + col), each unit is
// a bf16x8 holding k = kc*32 + q*8 + i at column col (pad cols zeroed).
// This is the EXACT LDS order -> global_load_lds reads are fully contiguous.
__global__ __launch_bounds__(256) void k_wsplit(const float* __restrict__ Wlast,
                                                short* __restrict__ Wsw) {
    int u = blockIdx.x * 256 + threadIdx.x;      // 0..32767
    int col = u & 1023;
    int q   = (u >> 10) & 3;
    int s   = u >> 12;                            // 0..7 = kc*2 + half
    int kc = s >> 1, half = s & 1;
    bf16x8 v;
    #pragma unroll
    for (int i = 0; i < 8; ++i) {
        int k = kc * 32 + q * 8 + i;
        float f = (col < VOCAB) ? Wlast[(size_t)k * VOCAB + col] : 0.f;
        unsigned b = __float_as_uint(f);
        if (half == 0) {
            v[i] = (short)(b >> 16);              // truncated bf16 hi
        } else {
            float fh = __uint_as_float(b & 0xFFFF0000u);
            v[i] = (short)(__float_as_uint(f - fh) >> 16);   // residual lo
        }
    }
    *(bf16x8*)&Wsw[(size_t)u * 8] = v;
}

// out[i] = softmax(h[i] @ Wlast + blast) via split-bf16 MFMA (3 products).
// 512 thr (8 waves = 4 col-groups x 2 row-groups), 32 nodes/block.
// W streamed as 8 units of 64 KB (hi/lo per K-chunk), double-buffered with
// counted vmcnt waits + raw s_barrier (prefetch never drained). Stores go
// through an LDS transpose (reusing the W buffers) -> coalesced dwordx4.
__global__ __launch_bounds__(512) void k_final_mfma(float* __restrict__ base,
                                                    const short* __restrict__ Wsw,
                                                    const float* __restrict__ blast,
                                                    int h_off) {
    const int t = threadIdx.x;
    const int lane = t & 63, w = t >> 6;
    const int cg = w & 3;        // col group: cols [cg*256, cg*256+256)
    const int rg = w >> 2;       // row group: rows [rg*16, rg*16+16)
    const int q = lane >> 4;     // k-quad within a 32-K step
    const int lr = lane & 15;
    const int i0 = blockIdx.x * 32;

    // 133120 B: as shorts = 2 staging buffers of 32768 (64 KB each);
    // as floats = [32][1040] store-transpose buffer (pad 1040 -> 2-way banks)
    __shared__ __align__(16) char smem[133120];
    short* sW = (short*)smem;
    float* sF = (float*)smem;
    __shared__ float smax[4][32];
    __shared__ float ssum[4][32];

    // ---- A fragments from global first (compiler drains their vmcnt before
    // our counted staging waits -> clean accounting). row = lane&15 (+rg*16),
    // k = kc*32 + q*8 + i
    bf16x8 ah[4], al[4];
    {
        const int arow = i0 + rg * 16 + lr;
        const float* hrow = base + (size_t)arow * ROWSTR + h_off + q * 8;
        #pragma unroll
        for (int kc = 0; kc < 4; ++kc) {
            float4 f0 = ((const float4*)(hrow + kc * 32))[0];
            float4 f1 = ((const float4*)(hrow + kc * 32))[1];
            float f[8] = {f0.x, f0.y, f0.z, f0.w, f1.x, f1.y, f1.z, f1.w};
            #pragma unroll
            for (int u2 = 0; u2 < 8; ++u2) {
                unsigned b = __float_as_uint(f[u2]);
                ah[kc][u2] = (short)(b >> 16);
                float fh = __uint_as_float(b & 0xFFFF0000u);
                al[kc][u2] = (short)(__float_as_uint(f[u2] - fh) >> 16);
            }
        }
    }

    // stage unit s into buffer b: 8 gload16 per thread, fully contiguous
    #define STAGEU(s, b) { \
        const short* gsrc = Wsw + (size_t)(s) * 32768; \
        short* ldst = sW + (size_t)(b) * 32768; \
        _Pragma("unroll") \
        for (int jj = 0; jj < 8; ++jj) { \
            int uu = t + jj * 512; \
            gload16(gsrc + (size_t)uu * 8, ldst + (size_t)uu * 8); \
        } }

    STAGEU(0, 0);
    STAGEU(1, 1);

    f32x4 acc[16];
    #pragma unroll
    for (int tt = 0; tt < 16; ++tt) acc[tt] = (f32x4){0.f, 0.f, 0.f, 0.f};

    // ---- unit loop: u = kc*2 + half; buf = u&1. Counted waits: 8 loads/wave
    // per unit; two units in flight.
    #pragma unroll
    for (int u = 0; u < 8; ++u) {
        if (u < 7) asm volatile("s_waitcnt vmcnt(8)" ::: "memory");
        else       asm volatile("s_waitcnt vmcnt(0)" ::: "memory");
        __builtin_amdgcn_s_barrier();
        const short* B = sW + (size_t)(u & 1) * 32768;
        const int kc = u >> 1;
        __builtin_amdgcn_s_setprio(1);
        #pragma unroll
        for (int tt = 0; tt < 16; ++tt) {
            int col = cg * 256 + tt * 16 + lr;
            bf16x8 wv = *(const bf16x8*)&B[((size_t)q * 1024 + col) * 8];
            if ((u & 1) == 0) {   // hi unit: ah*wh + al*wh
                acc[tt] = __builtin_amdgcn_mfma_f32_16x16x32_bf16(ah[kc], wv, acc[tt], 0, 0, 0);
                acc[tt] = __builtin_amdgcn_mfma_f32_16x16x32_bf16(al[kc], wv, acc[tt], 0, 0, 0);
            } else {              // lo unit: ah*wl
                acc[tt] = __builtin_amdgcn_mfma_f32_16x16x32_bf16(ah[kc], wv, acc[tt], 0, 0, 0);
            }
        }
        __builtin_amdgcn_s_setprio(0);
        __builtin_amdgcn_s_barrier();
        if (u + 2 < 8) { STAGEU(u + 2, u & 1); }
    }
    #undef STAGEU

    // ---- bias (per column; all 4 C rows share the lane's column)
    #pragma unroll
    for (int tt = 0; tt < 16; ++tt) {
        int col = cg * 256 + tt * 16 + lr;
        float bb = (col < VOCAB) ? blast[col] : 0.f;
        acc[tt][0] += bb; acc[tt][1] += bb; acc[tt][2] += bb; acc[tt][3] += bb;
    }

    // ---- softmax. C layout: col = lane&15, row-in-tile = q*4 + r
    float pm[4];
    #pragma unroll
    for (int r = 0; r < 4; ++r) pm[r] = -INFINITY;
    #pragma unroll
    for (int tt = 0; tt < 16; ++tt) {
        int col = cg * 256 + tt * 16 + lr;
        if (col < VOCAB) {
            #pragma unroll
            for (int r = 0; r < 4; ++r) pm[r] = fmaxf(pm[r], acc[tt][r]);
        }
    }
    #pragma unroll
    for (int s = 1; s < 16; s <<= 1)
        #pragma unroll
        for (int r = 0; r < 4; ++r)
            pm[r] = fmaxf(pm[r], __shfl_xor(pm[r], s, 64));
    if (lr == 0) {
        #pragma unroll
        for (int r = 0; r < 4; ++r) smax[cg][rg * 16 + q * 4 + r] = pm[r];
    }
    __syncthreads();
    float M[4];
    #pragma unroll
    for (int r = 0; r < 4; ++r) {
        int row = rg * 16 + q * 4 + r;
        M[r] = fmaxf(fmaxf(smax[0][row], smax[1][row]),
                     fmaxf(smax[2][row], smax[3][row]));
    }

    float ps[4] = {0.f, 0.f, 0.f, 0.f};
    #pragma unroll
    for (int tt = 0; tt < 16; ++tt) {
        int col = cg * 256 + tt * 16 + lr;
        bool valid = (col < VOCAB);
        #pragma unroll
        for (int r = 0; r < 4; ++r) {
            float e = valid ? __expf(acc[tt][r] - M[r]) : 0.f;
            acc[tt][r] = e;
            ps[r] += e;
        }
    }
    #pragma unroll
    for (int s = 1; s < 16; s <<= 1)
        #pragma unroll
        for (int r = 0; r < 4; ++r)
            ps[r] += __shfl_xor(ps[r], s, 64);
    if (lr == 0) {
        #pragma unroll
        for (int r = 0; r < 4; ++r) ssum[cg][rg * 16 + q * 4 + r] = ps[r];
    }
    __syncthreads();
    float inv[4];
    #pragma unroll
    for (int r = 0; r < 4; ++r) {
        int row = rg * 16 + q * 4 + r;
        float S = (ssum[0][row] + ssum[1][row]) + (ssum[2][row] + ssum[3][row]);
        inv[r] = 1.0f / S;
    }

    // ---- transpose probs through LDS (staging buffers are dead now; the
    // last unit-loop barrier ordered all sW reads before these writes)
    #pragma unroll
    for (int tt = 0; tt < 16; ++tt) {
        int col = cg * 256 + tt * 16 + lr;
        #pragma unroll
        for (int r = 0; r < 4; ++r) {
            int row = rg * 16 + q * 4 + r;
            sF[row * 1040 + col] = acc[tt][r] * inv[r];
        }
    }
    __syncthreads();

    // ---- coalesced store: 32 rows x 250 float4
    for (int idx = t; idx < 32 * 250; idx += 512) {
        int row = idx / 250;
        int c4  = idx - row * 250;
        float4 v = *(const float4*)&sF[row * 1040 + c4 * 4];
        *(float4*)&base[(size_t)(i0 + row) * ROWSTR + c4 * 4] = v;
    }
}

extern "C" void kernel_launch(void* const* d_in, const int* in_sizes, int n_in,
                              void* d_out, int out_size, void* d_ws, size_t ws_size,
                              hipStream_t stream) {
    (void)in_sizes; (void)n_in; (void)out_size; (void)ws_size;
    const int*   x     = (const int*)d_in[0];
    const int*   ei    = (const int*)d_in[1];
    const float* emb   = (const float*)d_in[2];
    const float* Wl    = (const float*)d_in[3];
    const float* bl    = (const float*)d_in[4];
    const float* Wr    = (const float*)d_in[5];
    const float* Wlast = (const float*)d_in[6];
    const float* blast = (const float*)d_in[7];
    float* base = (float*)d_out;
    const int* src = ei;
    const int* dst = ei + N_EDGES;

    short* Wsw = (short*)d_ws;                   // 32768 units x 16 B = 512 KB

    const int EG = (N_EDGES + 255) / 256;

    k_wsplit<<<dim3(128), dim3(256), 0, stream>>>(Wlast, Wsw);
    k_embed<<<dim3(N_NODES), dim3(HID), 0, stream>>>(base, x, emb);
    k_hist<<<dim3(EG), dim3(256), 0, stream>>>(base, dst);
    k_chunk_sums<<<dim3(NBLK), dim3(256), 0, stream>>>(base);
    k_scan_top<<<dim3(1), dim3(64), 0, stream>>>(base);
    k_scan_apply<<<dim3(NBLK), dim3(256), 0, stream>>>(base);
    k_build<<<dim3(EG), dim3(256), 0, stream>>>(base, src, dst);

    int in_off = OFF_H0, out_off = OFF_H1;
    for (int l = 0; l < 3; ++l) {
        k_layer<<<dim3(N_NODES / TNB), dim3(256), 0, stream>>>(
            base, Wl + (size_t)l * HID * HID, bl + (size_t)l * HID,
            Wr + (size_t)l * HID * HID, in_off, out_off);
        int tmp = in_off; in_off = out_off; out_off = tmp;
    }
    // after 3 layers h lives at in_off (== OFF_H1)
    k_final_mfma<<<dim3(N_NODES / 32), dim3(512), 0, stream>>>(
        base, Wsw, blast, in_off);
}